// Round 1
// baseline (34.407 us; speedup 1.0000x reference)
//
#include <hip/hip_runtime.h>

// SATD loss: t = H * (input - label)_8x8block * H  (H = 8x8 Sylvester Hadamard),
// result = mean(|t|).  lmul == rmul == H because r1,r2,r3 are symmetric and
// pairwise commuting tensor-factor butterflies, so we hardcode the fast
// Walsh-Hadamard transform (3 butterfly stages each side).

#define B_ 16
#define C_ 3
#define H_ 512
#define W_ 512
#define N_TOTAL ((float)((long long)B_ * C_ * H_ * W_))   // 12,582,912

__device__ __forceinline__ void fht8(float* x) {
#pragma unroll
    for (int s = 4; s >= 1; s >>= 1) {
#pragma unroll
        for (int i = 0; i < 8; ++i) {
            if ((i & s) == 0) {
                float u = x[i], w = x[i + s];
                x[i] = u + w;
                x[i + s] = u - w;
            }
        }
    }
}

__global__ __launch_bounds__(256) void satd_kernel(const float* __restrict__ a,
                                                   const float* __restrict__ b,
                                                   float* __restrict__ out) {
    int g = blockIdx.x * 256 + threadIdx.x;     // one thread per 8x8 block
    int bx  = g & 63;          // block col (64 per image row)
    int by  = (g >> 6) & 63;   // block row
    int img = g >> 12;         // b*c image index, [0,48)

    size_t base = ((size_t)img * 512 + (size_t)by * 8) * 512 + (size_t)bx * 8;

    float v[8][8];
#pragma unroll
    for (int r = 0; r < 8; ++r) {
        const float4* pa = reinterpret_cast<const float4*>(a + base + (size_t)r * 512);
        const float4* pb = reinterpret_cast<const float4*>(b + base + (size_t)r * 512);
        float4 a0 = pa[0], a1 = pa[1];
        float4 b0 = pb[0], b1 = pb[1];
        float d[8] = {a0.x - b0.x, a0.y - b0.y, a0.z - b0.z, a0.w - b0.w,
                      a1.x - b1.x, a1.y - b1.y, a1.z - b1.z, a1.w - b1.w};
        fht8(d);
#pragma unroll
        for (int c = 0; c < 8; ++c) v[r][c] = d[c];
    }

    float s = 0.0f;
#pragma unroll
    for (int c = 0; c < 8; ++c) {
        float col[8];
#pragma unroll
        for (int r = 0; r < 8; ++r) col[r] = v[r][c];
        fht8(col);
#pragma unroll
        for (int r = 0; r < 8; ++r) s += fabsf(col[r]);
    }

    // wave (64-lane) reduction
#pragma unroll
    for (int off = 32; off >= 1; off >>= 1) s += __shfl_down(s, off);

    __shared__ float ws[4];
    int lane = threadIdx.x & 63;
    int wid  = threadIdx.x >> 6;
    if (lane == 0) ws[wid] = s;
    __syncthreads();
    if (threadIdx.x == 0) {
        float tot = ws[0] + ws[1] + ws[2] + ws[3];
        atomicAdd(out, tot * (1.0f / N_TOTAL));
    }
}

extern "C" void kernel_launch(void* const* d_in, const int* in_sizes, int n_in,
                              void* d_out, int out_size, void* d_ws, size_t ws_size,
                              hipStream_t stream) {
    const float* a = (const float*)d_in[0];   // input
    const float* b = (const float*)d_in[1];   // label
    float* out = (float*)d_out;

    hipMemsetAsync(out, 0, sizeof(float), stream);
    satd_kernel<<<dim3(768), dim3(256), 0, stream>>>(a, b, out);
}